// Round 10
// baseline (233.823 us; speedup 1.0000x reference)
//
#include <hip/hip_runtime.h>
#include <hip/hip_bf16.h>

#define B_ 4
#define S_ 2048
#define HD 1024
#define NH 8
#define DK 128
#define WA 67
#define WPAD 80      // cD^T rows: 0..66 data, 67 = ones (l-column), 68..79 zero

typedef __attribute__((ext_vector_type(8))) short short8;
typedef __attribute__((ext_vector_type(4))) short short4v;
typedef __attribute__((ext_vector_type(4))) float floatx4;

// hardware exp2: one v_exp_f32 (avoid __exp2f - glibc macro collision)
__device__ __forceinline__ float hexp2(float x) { return __builtin_amdgcn_exp2f(x); }

__device__ __forceinline__ short f2bf(float f) {
    union { float f; unsigned u; } c; c.f = f;
    unsigned u = c.u;
    u += 0x7FFF + ((u >> 16) & 1);          // RTNE
    return (short)(u >> 16);
}
__device__ __forceinline__ float bf2f(short s) {
    union { unsigned u; float f; } c; c.u = ((unsigned)(unsigned short)s) << 16;
    return c.f;
}
__device__ __forceinline__ short f2bf_trunc(float f) {
    union { float f; unsigned u; } c; c.f = f;
    return (short)(c.u >> 16);
}

// async 16B global->LDS DMA; LDS dest = wave-uniform base, lane i lands at
// base + i*16. Per-lane global address is free to choose -> XOR swizzle there.
__device__ __forceinline__ void glds16(void* lds, const void* g) {
    __builtin_amdgcn_global_load_lds(
        (const __attribute__((address_space(1))) unsigned*)g,
        (__attribute__((address_space(3))) unsigned*)lds, 16, 0, 0);
}

#define VM0  asm volatile("s_waitcnt vmcnt(0)" ::: "memory")
#define VM10 asm volatile("s_waitcnt vmcnt(10)" ::: "memory")
#define BARRIER do { asm volatile("" ::: "memory"); \
                     __builtin_amdgcn_s_barrier(); \
                     asm volatile("" ::: "memory"); } while (0)

// db4 filters, pre-reversed for correlation: F[j] = DEC_*[7-j]
__device__ __constant__ float FLO[8] = {
    0.23037781330885523f,  0.7148465705525415f,  0.6308807679295904f,
   -0.02798376941698385f, -0.18703481171888114f, 0.030841381835986965f,
    0.032883011666982945f, -0.010597401784997278f };
__device__ __constant__ float FHI[8] = {
   -0.010597401784997278f, -0.032883011666982945f, 0.030841381835986965f,
    0.18703481171888114f,  -0.02798376941698385f, -0.6308807679295904f,
    0.7148465705525415f,   -0.23037781330885523f };

// ------- fp32 -> bf16 bulk convert, all four inputs in ONE launch ----------
__global__ __launch_bounds__(256) void cvt_all(
    const float* __restrict__ x,  const float* __restrict__ wq,
    const float* __restrict__ wk, const float* __restrict__ wv,
    short* __restrict__ xb, short* __restrict__ wb)
{
    const size_t w_elems = (size_t)HD * HD;
    int blk = blockIdx.x;
    const float* src; short* dst; int lb;
    if (blk < 4096)      { src = x;  dst = xb;               lb = blk; }
    else if (blk < 4608) { src = wq; dst = wb;               lb = blk - 4096; }
    else if (blk < 5120) { src = wk; dst = wb + w_elems;     lb = blk - 4608; }
    else                 { src = wv; dst = wb + 2 * w_elems; lb = blk - 5120; }
    int i = lb * 256 + threadIdx.x;
    const float4* s = (const float4*)src + (size_t)i * 2;
    float4 f0 = s[0], f1 = s[1];
    short8 o;
    o[0] = f2bf(f0.x); o[1] = f2bf(f0.y); o[2] = f2bf(f0.z); o[3] = f2bf(f0.w);
    o[4] = f2bf(f1.x); o[5] = f2bf(f1.y); o[6] = f2bf(f1.z); o[7] = f2bf(f1.w);
    *((short8*)dst + i) = o;
}

// ------- QKV projection + fused DWT: 128x128xBK64, dbuf, 2 blocks/CU -------
// R3-EXACT (74.8us measured, best of r3/r7/r8 sweep; BK=32 variants lose to
// barrier-interval doubling). Tile 128x128, BK=64, 4 waves (2x2, wave tile
// 64x64). 64KB LDS dbuf -> 2 blocks/CU; cross-block TLP hides the per-tile
// drain. Grid 64x24 = 1536 = 3 clean co-residency rounds. Per K-tile: stage
// tile t+1 FIRST, then 2x {8 ds_read_b128, setprio(1), 16 MFMA, setprio(0)},
// then ONE vmcnt(0)+barrier at the tile boundary.  [do not touch]
// z==2 (V): tile = one head x 128 s-rows; epilogue restages as Cs[128][130]
// (stride 65 dwords, odd -> conflict-free) and computes the db4 DWT:
// cA -> out2, cD^T (+ones row 67, zero rows 68..79) -> cdt.
__global__ __launch_bounds__(256, 2) void qkv_gemm(
    const short* __restrict__ xb, const short* __restrict__ Wb,
    short* __restrict__ Qb, short* __restrict__ Kb,
    float* __restrict__ outA, short* __restrict__ cdt)
{
    __shared__ __align__(16) short SM[32768];   // 64KB: [A0|A1|B0|B1] 16KB each
    const int tid  = threadIdx.x;
    const int wid  = tid >> 6;            // 0..3
    const int lane = tid & 63;
    const int l15  = lane & 15;
    const int quad = lane >> 4;
    const int rx   = l15 & 7;
    const int wm   = wid >> 1;            // 0..1  (m-position of wave)
    const int wn   = wid & 1;             // 0..1  (n-position of wave)
    const int m0 = blockIdx.x * 128;
    const int by = blockIdx.y;            // 0..23
    const int z  = by >> 3;               // 0=Q 1=K 2=V
    const int n0 = (by & 7) * 128;        // n-offset within the z-th weight
    const short* W = Wb + (size_t)z * HD * HD;
    // q scale folded with log2(e) so attention softmax can use exp2
    const float scale = (z == 0) ? 0.12751743786072596f : 1.0f;
    const int srow = lane >> 3;                 // staging: 8 lanes per 128B row
    const int sch  = (lane & 7) ^ srow;         // XOR-swizzled source chunk

    floatx4 acc[4][4] = {};

    auto Abuf = [&](int bf) -> short* { return SM + bf * 8192; };
    auto Bbuf = [&](int bf) -> short* { return SM + 16384 + bf * 8192; };

    // stage one 128x64 tile half: 16 x 1KB issues -> 4 per wave
    auto stA = [&](int bf, int t) {
        short* d = Abuf(bf);
        #pragma unroll
        for (int i = 0; i < 4; ++i) {
            int ti = wid * 4 + i;
            glds16(d + ti * 512,
                   xb + (size_t)(m0 + ti * 8 + srow) * HD + t * 64 + sch * 8);
        }
    };
    auto stB = [&](int bf, int t) {
        short* d = Bbuf(bf);
        #pragma unroll
        for (int i = 0; i < 4; ++i) {
            int ti = wid * 4 + i;
            glds16(d + ti * 512,
                   W + (size_t)(n0 + ti * 8 + srow) * HD + t * 64 + sch * 8);
        }
    };

    // prologue: tile 0 -> buf 0, full drain once
    stA(0, 0); stB(0, 0);
    VM0; BARRIER;

    for (int t = 0; t < 16; ++t) {
        const int cur = t & 1, nxt = cur ^ 1;
        if (t < 15) { stA(nxt, t + 1); stB(nxt, t + 1); }   // issue-early
        const short* Ab = Abuf(cur);
        const short* Bb = Bbuf(cur);
        #pragma unroll
        for (int ks = 0; ks < 2; ++ks) {
            short8 af[4], bf4[4];
            #pragma unroll
            for (int mt = 0; mt < 4; ++mt)
                af[mt] = *(const short8*)
                    &Ab[(wm * 64 + mt * 16 + l15) * 64 + (((ks * 4 + quad) ^ rx) * 8)];
            #pragma unroll
            for (int nt = 0; nt < 4; ++nt)
                bf4[nt] = *(const short8*)
                    &Bb[(wn * 64 + nt * 16 + l15) * 64 + (((ks * 4 + quad) ^ rx) * 8)];
            __builtin_amdgcn_s_setprio(1);
            #pragma unroll
            for (int mt = 0; mt < 4; ++mt)
                #pragma unroll
                for (int nt = 0; nt < 4; ++nt)
                    acc[mt][nt] = __builtin_amdgcn_mfma_f32_16x16x32_bf16(
                        af[mt], bf4[nt], acc[mt][nt], 0, 0, 0);
            __builtin_amdgcn_s_setprio(0);
        }
        VM0;           // tile t+1's 8 loads: issued a full tile ago -> ~0 wait
        BARRIER;       // buf[nxt] visible to all; all waves done with buf[cur]
    }

    // C layout per fragment: col = l15 (N), row = quad*4+reg (M).
    if (z != 2) {
        short* Yb = (z == 0) ? Qb : Kb;
        #pragma unroll
        for (int mt = 0; mt < 4; ++mt)
            #pragma unroll
            for (int nt = 0; nt < 4; ++nt)
                #pragma unroll
                for (int reg = 0; reg < 4; ++reg) {
                    int rg = m0 + wm * 64 + mt * 16 + quad * 4 + reg;
                    int cg = n0 + wn * 64 + nt * 16 + l15;
                    int b = rg >> 11, s = rg & 2047;
                    int h = cg >> 7,  d = cg & 127;
                    Yb[((size_t)(b * NH + h) * S_ + s) * DK + d] =
                        f2bf(acc[mt][nt][reg] * scale);
                }
        return;
    }
    // ---- z==2: V tile (1 head x 128 s-rows) -> LDS, fused db4 DWT ----
    short* Cs = SM;                      // 128 x 130 shorts = 33.3KB (in 64KB)
    #pragma unroll
    for (int mt = 0; mt < 4; ++mt)
        #pragma unroll
        for (int nt = 0; nt < 4; ++nt)
            #pragma unroll
            for (int reg = 0; reg < 4; ++reg) {
                int r = wm * 64 + mt * 16 + quad * 4 + reg;
                int c = wn * 64 + nt * 16 + l15;
                Cs[r * 130 + c] = f2bf(acc[mt][nt][reg]);
            }
    __syncthreads();
    const int rl    = tid & 127;                 // local V row (s)
    const int chunk = tid >> 7;                  // t-half 0/1
    const int rg = m0 + rl;
    const int b = rg >> 11, s = rg & 2047;
    const int bh = b * NH + (by & 7);            // h == by&7
    const short* vr = Cs + rl * 130;
    auto getv = [&](int i) -> float {
        int k = (i < 6) ? (5 - i) : (i < 134) ? (i - 6) : (261 - i);
        return bf2f(vr[k]);
    };
    const int t0 = chunk * 34;
    const int t1 = (chunk == 0) ? 34 : WA;
    float win[8];
    #pragma unroll
    for (int j = 0; j < 8; ++j) win[j] = getv(2 * t0 + j);
    float* oA = outA + ((size_t)bh * S_ + s) * WA;
    for (int t = t0; t < t1; ++t) {
        float lo = 0.f, hi = 0.f;
        #pragma unroll
        for (int j = 0; j < 8; ++j) { lo += win[j] * FLO[j]; hi += win[j] * FHI[j]; }
        oA[t] = lo;                                          // contiguous per thread
        cdt[((size_t)bh * WPAD + t) * S_ + s] = f2bf(hi);    // lane-coalesced over s
        #pragma unroll
        for (int j = 0; j < 6; ++j) win[j] = win[j + 2];
        if (t + 1 < t1) { win[6] = getv(2 * t + 8); win[7] = getv(2 * t + 9); }
    }
    if (chunk == 1) {
        #pragma unroll
        for (int w = WA; w < WPAD; ++w)
            cdt[((size_t)bh * WPAD + w) * S_ + s] =
                (w == 67) ? (short)0x3F80 : (short)0;   // ones row 67 (l), else 0
    }
}

// ---------------- flash attention: out1 = softmax(QK^T) @ cD ----------------
// R10: CROSS-KT SOFTWARE PIPELINE (T15 mechanism). r9 refuted LDS-BW-bound
// (-30% LDS bytes = 0% speedup); the limiter is the serial intra-wave chain
// QK^T -> exp2/pack -> PV (MfmaUtil 30 + VALUBusy 25 alternate, never
// overlap). Now iteration kt runs:
//   A: QK^T[kt+1] (Ks[nxt])   -- independent of...
//   B: PV[kt]     (ptw=P[kt] written last iter, Ds[kt%3])
//   C: softmax[kt+1] -> ptw   -- sc retired during B's ~100cy of MFMA
// No phase waits on an in-flight result. ptw WAR (B reads, C writes, same
// wave-private addresses) is safe: DS ops within a wave complete in order.
// Buffers: Ks dbuf (parity), Ds TRIPLE (kt%3) so BOTH K[kt+2] and D[kt+2]
// stage at the TOP of iter kt into reader-free buffers -> ONE barrier and
// ONE counted vmcnt(10) per iteration (completes K[kt+1]+D[kt], always
// leaves the newest D batch of 10 in flight -- never drains mid-loop).
// K slack = 1 iter, D slack = 2 iters. LDS 32+30+16 = 78KB -> 2 blocks/CU.
// Per-output arithmetic order identical to r4 -> absmax unchanged.
__global__ __launch_bounds__(256, 2) void attn_kernel(
    const short* __restrict__ Qb, const short* __restrict__ Kb,
    const short* __restrict__ cdt, float* __restrict__ out1)
{
    __shared__ __align__(16) short Ks[2][64 * 128];      // 32KB
    __shared__ __align__(16) short Ds[3 * WPAD * 64];    // 30KB (triple)
    __shared__ __align__(16) short Pt[8 * 1024];         // 16KB wave-private P
    const int tid  = threadIdx.x;
    const int wv   = tid >> 6;
    const int lane = tid & 63;
    const int l15  = lane & 15;
    const int quad = lane >> 4;
    const int qt = blockIdx.x;           // 0..15 (128 q-rows each)
    const int bh = blockIdx.y;           // 0..31
    const int b = bh >> 3, h = bh & 7;
    const int rxor = l15 & 7;

    // Q fragments from global, once. Lane layout = row l15, k = quad*8+j
    // (identical for A- and B-operands, so they serve as B in S^T = K Q^T).
    short8 aq[2][4];
    #pragma unroll
    for (int n = 0; n < 2; ++n) {
        const short* qrow =
            Qb + ((size_t)bh * S_ + qt * 128 + wv * 32 + n * 16 + l15) * DK;
        #pragma unroll
        for (int s4 = 0; s4 < 4; ++s4)
            aq[n][s4] = *(const short8*)(qrow + s4 * 32 + quad * 8);
    }

    floatx4 O[2][5] = {};                // j=4 tile col 67 accumulates l

    const short* kbase = Kb + (size_t)bh * S_ * DK;
    const int krow = lane >> 4;                    // K staging: 4 rows/issue
    const int kch  = (lane & 15);
    const int drow = lane >> 3;                    // D staging: 8 rows/issue
    const int dch  = (lane & 7) ^ (drow & 7);
    short* ptw = Pt + wv * 2048;                   // this wave's P (2 tiles)

    auto Dbuf = [&](int i) -> short* { return Ds + i * (WPAD * 64); };

    // stage K tile (64x256B, 16 issues -> 4/wave) / D tile (80x128B, 10 issues)
    auto stK = [&](int bf, int kt) {
        #pragma unroll
        for (int i = 0; i < 4; ++i) {
            int ti = wv * 4 + i;
            int r  = ti * 4 + krow;
            int ch = kch ^ (r & 7);
            glds16(&Ks[bf][ti * 512], kbase + ((size_t)kt * 64 + r) * DK + ch * 8);
        }
    };
    auto stD = [&](int bf, int kt) {
        #pragma unroll
        for (int i = 0; i < 3; ++i) {
            int t = wv + i * 4;
            if (t < 10) {
                int r = t * 8 + drow;
                glds16(Dbuf(bf) + t * 512,
                       cdt + ((size_t)bh * WPAD + r) * S_ + kt * 64 + dch * 8);
            }
        }
    };

    // prologue: tiles 0,1 staged; QK^T[0]+softmax fills ptw
    stK(0, 0); stD(0, 0);
    stK(1, 1); stD(1, 1);
    VM0; BARRIER;
    {
        floatx4 sc[2][4] = {};
        #pragma unroll
        for (int s4 = 0; s4 < 4; ++s4) {
            short8 kf[4];
            #pragma unroll
            for (int mt = 0; mt < 4; ++mt) {
                int ch = (s4 * 4 + quad) ^ rxor;
                kf[mt] = *(const short8*)&Ks[0][(mt * 16 + l15) * 128 + ch * 8];
            }
            __builtin_amdgcn_s_setprio(1);
            #pragma unroll
            for (int n = 0; n < 2; ++n)
                #pragma unroll
                for (int mt = 0; mt < 4; ++mt)
                    sc[n][mt] = __builtin_amdgcn_mfma_f32_16x16x32_bf16(
                        kf[mt], aq[n][s4], sc[n][mt], 0, 0, 0);
            __builtin_amdgcn_s_setprio(0);
        }
        #pragma unroll
        for (int n = 0; n < 2; ++n)
            #pragma unroll
            for (int mt = 0; mt < 4; ++mt) {
                short4v pk;
                #pragma unroll
                for (int reg = 0; reg < 4; ++reg)
                    pk[reg] = f2bf_trunc(hexp2(sc[n][mt][reg]));
                int ch = (mt * 2 + (quad >> 1)) ^ rxor;
                *(short4v*)&ptw[n * 1024 + l15 * 64 + ch * 8 + (quad & 1) * 4] = pk;
            }
    }

    for (int kt = 0; kt < 31; ++kt) {
        const int cur = kt & 1, nxt = cur ^ 1;
        VM10;      // completes K[kt+1] (read below) + all older (incl. D[kt]);
                   // leaves the newest D batch (10 loads) in flight
        BARRIER;   // staged tiles visible; prior readers of overwrite targets done
        if (kt <= 29) {
            stK(cur, kt + 2);                // Kbuf[cur]: K[kt] dead since iter kt-1
            stD((kt + 2) % 3, kt + 2);       // Dbuf[(kt+2)%3]: D[kt-1] dead
        }

        // --- A: QK^T[kt+1] on Ks[nxt] ---
        floatx4 sc[2][4] = {};
        #pragma unroll
        for (int s4 = 0; s4 < 4; ++s4) {
            short8 kf[4];
            #pragma unroll
            for (int mt = 0; mt < 4; ++mt) {
                int ch = (s4 * 4 + quad) ^ rxor;
                kf[mt] = *(const short8*)&Ks[nxt][(mt * 16 + l15) * 128 + ch * 8];
            }
            __builtin_amdgcn_s_setprio(1);
            #pragma unroll
            for (int n = 0; n < 2; ++n)
                #pragma unroll
                for (int mt = 0; mt < 4; ++mt)
                    sc[n][mt] = __builtin_amdgcn_mfma_f32_16x16x32_bf16(
                        kf[mt], aq[n][s4], sc[n][mt], 0, 0, 0);
            __builtin_amdgcn_s_setprio(0);
        }

        // --- B: PV[kt] using ptw (P[kt]) and Ds[kt%3] ---
        short8 ap[2][2];
        #pragma unroll
        for (int mt = 0; mt < 2; ++mt)
            #pragma unroll
            for (int ks = 0; ks < 2; ++ks) {
                int ch = (ks * 4 + quad) ^ rxor;
                ap[mt][ks] = *(const short8*)&ptw[mt * 1024 + l15 * 64 + ch * 8];
            }
        {
            const short* Dcur = Dbuf(kt % 3);
            #pragma unroll
            for (int j = 0; j < 5; ++j) {
                #pragma unroll
                for (int ks = 0; ks < 2; ++ks) {
                    int ch = (ks * 4 + quad) ^ rxor;
                    short8 bd = *(const short8*)&Dcur[(j * 16 + l15) * 64 + ch * 8];
                    __builtin_amdgcn_s_setprio(1);
                    #pragma unroll
                    for (int mt = 0; mt < 2; ++mt)
                        O[mt][j] = __builtin_amdgcn_mfma_f32_16x16x32_bf16(
                            ap[mt][ks], bd, O[mt][j], 0, 0, 0);
                    __builtin_amdgcn_s_setprio(0);
                }
            }
        }

        // --- C: softmax[kt+1] -> ptw (sc retired during B) ---
        #pragma unroll
        for (int n = 0; n < 2; ++n)
            #pragma unroll
            for (int mt = 0; mt < 4; ++mt) {
                short4v pk;
                #pragma unroll
                for (int reg = 0; reg < 4; ++reg)
                    pk[reg] = f2bf_trunc(hexp2(sc[n][mt][reg]));
                int ch = (mt * 2 + (quad >> 1)) ^ rxor;
                *(short4v*)&ptw[n * 1024 + l15 * 64 + ch * 8 + (quad & 1) * 4] = pk;
            }
    }
    // epilogue: PV[31] (D[31] is the last in-flight batch)
    VM0; BARRIER;
    {
        short8 ap[2][2];
        #pragma unroll
        for (int mt = 0; mt < 2; ++mt)
            #pragma unroll
            for (int ks = 0; ks < 2; ++ks) {
                int ch = (ks * 4 + quad) ^ rxor;
                ap[mt][ks] = *(const short8*)&ptw[mt * 1024 + l15 * 64 + ch * 8];
            }
        const short* Dcur = Dbuf(31 % 3);
        #pragma unroll
        for (int j = 0; j < 5; ++j) {
            #pragma unroll
            for (int ks = 0; ks < 2; ++ks) {
                int ch = (ks * 4 + quad) ^ rxor;
                short8 bd = *(const short8*)&Dcur[(j * 16 + l15) * 64 + ch * 8];
                __builtin_amdgcn_s_setprio(1);
                #pragma unroll
                for (int mt = 0; mt < 2; ++mt)
                    O[mt][j] = __builtin_amdgcn_mfma_f32_16x16x32_bf16(
                        ap[mt][ks], bd, O[mt][j], 0, 0, 0);
                __builtin_amdgcn_s_setprio(0);
            }
        }
    }
    // l(r) sits at element (row r, col 67) = lane (r>>2)*16+3, reg r&3 of j=4.
    float rl[2][4];
    #pragma unroll
    for (int mt = 0; mt < 2; ++mt)
        #pragma unroll
        for (int reg = 0; reg < 4; ++reg)
            rl[mt][reg] = 1.0f / __shfl(O[mt][4][reg], (quad << 4) | 3, 64);
    // epilogue: out1[b][q][h*67+w] = O * (1/l)   (w >= 67 dropped)
    #pragma unroll
    for (int mt = 0; mt < 2; ++mt)
        #pragma unroll
        for (int j = 0; j < 5; ++j) {
            int w = j * 16 + l15;
            if (w < WA) {
                #pragma unroll
                for (int reg = 0; reg < 4; ++reg) {
                    int qrow_g = qt * 128 + wv * 32 + mt * 16 + quad * 4 + reg;
                    out1[((size_t)(b * S_ + qrow_g)) * (NH * WA) + h * WA + w] =
                        O[mt][j][reg] * rl[mt][reg];
                }
            }
        }
}

extern "C" void kernel_launch(void* const* d_in, const int* in_sizes, int n_in,
                              void* d_out, int out_size, void* d_ws, size_t ws_size,
                              hipStream_t stream)
{
    const float* x  = (const float*)d_in[0];
    const float* Wq = (const float*)d_in[1];
    const float* Wk = (const float*)d_in[2];
    const float* Wv = (const float*)d_in[3];
    float* out = (float*)d_out;

    const size_t x_elems   = (size_t)B_ * S_ * HD;           // 8,388,608
    const size_t w_elems   = (size_t)HD * HD;                // 1,048,576
    const size_t qkv_elems = (size_t)B_ * NH * S_ * DK;      // 8,388,608
    short* xb  = (short*)d_ws;
    short* Wb  = xb + x_elems;                               // 3 concatenated
    short* Qb  = Wb + 3 * w_elems;
    short* Kb  = Qb + qkv_elems;
    short* cdt = Kb + qkv_elems;                             // (b,h,w=80,s) bf16
    float* out1 = out;                                       // (B,S,536)
    float* out2 = out + (size_t)B_ * S_ * NH * WA;           // (B,H,S,67)

    cvt_all<<<dim3(5632), 256, 0, stream>>>(x, Wq, Wk, Wv, xb, Wb);
    qkv_gemm<<<dim3(64, 24), 256, 0, stream>>>(xb, Wb, Qb, Kb, out2, cdt);
    attn_kernel<<<dim3(16, 32), 256, 0, stream>>>(Qb, Kb, cdt, out1);
}

// Round 11
// 223.691 us; speedup vs baseline: 1.0453x; 1.0453x over previous
//
#include <hip/hip_runtime.h>
#include <hip/hip_bf16.h>

#define B_ 4
#define S_ 2048
#define HD 1024
#define NH 8
#define DK 128
#define WA 67
#define WPAD 80      // cD^T rows: 0..66 data, 67 = ones (l-column), 68..79 zero

typedef __attribute__((ext_vector_type(8))) short short8;
typedef __attribute__((ext_vector_type(4))) short short4v;
typedef __attribute__((ext_vector_type(4))) float floatx4;

// hardware exp2: one v_exp_f32 (avoid __exp2f - glibc macro collision)
__device__ __forceinline__ float hexp2(float x) { return __builtin_amdgcn_exp2f(x); }

__device__ __forceinline__ short f2bf(float f) {
    union { float f; unsigned u; } c; c.f = f;
    unsigned u = c.u;
    u += 0x7FFF + ((u >> 16) & 1);          // RTNE
    return (short)(u >> 16);
}
__device__ __forceinline__ float bf2f(short s) {
    union { unsigned u; float f; } c; c.u = ((unsigned)(unsigned short)s) << 16;
    return c.f;
}
__device__ __forceinline__ short f2bf_trunc(float f) {
    union { float f; unsigned u; } c; c.f = f;
    return (short)(c.u >> 16);
}

// async 16B global->LDS DMA; LDS dest = wave-uniform base, lane i lands at
// base + i*16. Per-lane global address is free to choose -> XOR swizzle there.
__device__ __forceinline__ void glds16(void* lds, const void* g) {
    __builtin_amdgcn_global_load_lds(
        (const __attribute__((address_space(1))) unsigned*)g,
        (__attribute__((address_space(3))) unsigned*)lds, 16, 0, 0);
}

#define VM0 asm volatile("s_waitcnt vmcnt(0)" ::: "memory")
#define BARRIER do { asm volatile("" ::: "memory"); \
                     __builtin_amdgcn_s_barrier(); \
                     asm volatile("" ::: "memory"); } while (0)

// db4 filters, pre-reversed for correlation: F[j] = DEC_*[7-j]
__device__ __constant__ float FLO[8] = {
    0.23037781330885523f,  0.7148465705525415f,  0.6308807679295904f,
   -0.02798376941698385f, -0.18703481171888114f, 0.030841381835986965f,
    0.032883011666982945f, -0.010597401784997278f };
__device__ __constant__ float FHI[8] = {
   -0.010597401784997278f, -0.032883011666982945f, 0.030841381835986965f,
    0.18703481171888114f,  -0.02798376941698385f, -0.6308807679295904f,
    0.7148465705525415f,   -0.23037781330885523f };

// ------- fp32 -> bf16 bulk convert, all four inputs in ONE launch ----------
__global__ __launch_bounds__(256) void cvt_all(
    const float* __restrict__ x,  const float* __restrict__ wq,
    const float* __restrict__ wk, const float* __restrict__ wv,
    short* __restrict__ xb, short* __restrict__ wb)
{
    const size_t w_elems = (size_t)HD * HD;
    int blk = blockIdx.x;
    const float* src; short* dst; int lb;
    if (blk < 4096)      { src = x;  dst = xb;               lb = blk; }
    else if (blk < 4608) { src = wq; dst = wb;               lb = blk - 4096; }
    else if (blk < 5120) { src = wk; dst = wb + w_elems;     lb = blk - 4608; }
    else                 { src = wv; dst = wb + 2 * w_elems; lb = blk - 5120; }
    int i = lb * 256 + threadIdx.x;
    const float4* s = (const float4*)src + (size_t)i * 2;
    float4 f0 = s[0], f1 = s[1];
    short8 o;
    o[0] = f2bf(f0.x); o[1] = f2bf(f0.y); o[2] = f2bf(f0.z); o[3] = f2bf(f0.w);
    o[4] = f2bf(f1.x); o[5] = f2bf(f1.y); o[6] = f2bf(f1.z); o[7] = f2bf(f1.w);
    *((short8*)dst + i) = o;
}

// ------- QKV projection + fused DWT: 128x128xBK64, dbuf, 2 blocks/CU -------
// SESSION BEST (74.8us measured r3; BK=32 variants r7/r8 lose to barrier-
// interval doubling; 256-wide tiles r1/r2 lose to 1-block/CU lockstep).
// One fused GEMM over N=3072 (Wq|Wk|Wv). Tile 128(M)x128(N), BK=64, 4 waves
// (2x2, wave tile 64x64). 64KB LDS double-buffer -> 2 blocks/CU (16 waves/CU):
// cross-block TLP hides the per-tile drain. Grid 64x24 = 1536 blocks = 3 clean
// co-residency rounds of 512. Per K-tile (T3-minimal recipe): stage tile t+1
// FIRST (8 glds into buf nxt), then 2x {8 ds_read_b128, setprio(1), 16 MFMA,
// setprio(0)} on buf cur, then ONE vmcnt(0)+barrier at the tile boundary --
// the drain has a full tile (~700cy) of issue-to-wait cover; residue is
// covered by the co-resident block.
// z==2 (V): tile = one head x 128 s-rows; epilogue restages it as
// Cs[128][130] (stride 65 dwords, odd -> conflict-free column reads) aliased
// on the LDS pool and computes the db4 DWT in-block: cA -> out2, cD^T
// (+ones row 67, zero rows 68..79) -> cdt.
__global__ __launch_bounds__(256, 2) void qkv_gemm(
    const short* __restrict__ xb, const short* __restrict__ Wb,
    short* __restrict__ Qb, short* __restrict__ Kb,
    float* __restrict__ outA, short* __restrict__ cdt)
{
    __shared__ __align__(16) short SM[32768];   // 64KB: [A0|A1|B0|B1] 16KB each
    const int tid  = threadIdx.x;
    const int wid  = tid >> 6;            // 0..3
    const int lane = tid & 63;
    const int l15  = lane & 15;
    const int quad = lane >> 4;
    const int rx   = l15 & 7;
    const int wm   = wid >> 1;            // 0..1  (m-position of wave)
    const int wn   = wid & 1;             // 0..1  (n-position of wave)
    const int m0 = blockIdx.x * 128;
    const int by = blockIdx.y;            // 0..23
    const int z  = by >> 3;               // 0=Q 1=K 2=V
    const int n0 = (by & 7) * 128;        // n-offset within the z-th weight
    const short* W = Wb + (size_t)z * HD * HD;
    // q scale folded with log2(e) so attention softmax can use exp2
    const float scale = (z == 0) ? 0.12751743786072596f : 1.0f;
    const int srow = lane >> 3;                 // staging: 8 lanes per 128B row
    const int sch  = (lane & 7) ^ srow;         // XOR-swizzled source chunk

    floatx4 acc[4][4] = {};

    auto Abuf = [&](int bf) -> short* { return SM + bf * 8192; };
    auto Bbuf = [&](int bf) -> short* { return SM + 16384 + bf * 8192; };

    // stage one 128x64 tile half: 16 x 1KB issues -> 4 per wave
    auto stA = [&](int bf, int t) {
        short* d = Abuf(bf);
        #pragma unroll
        for (int i = 0; i < 4; ++i) {
            int ti = wid * 4 + i;
            glds16(d + ti * 512,
                   xb + (size_t)(m0 + ti * 8 + srow) * HD + t * 64 + sch * 8);
        }
    };
    auto stB = [&](int bf, int t) {
        short* d = Bbuf(bf);
        #pragma unroll
        for (int i = 0; i < 4; ++i) {
            int ti = wid * 4 + i;
            glds16(d + ti * 512,
                   W + (size_t)(n0 + ti * 8 + srow) * HD + t * 64 + sch * 8);
        }
    };

    // prologue: tile 0 -> buf 0, full drain once
    stA(0, 0); stB(0, 0);
    VM0; BARRIER;

    for (int t = 0; t < 16; ++t) {
        const int cur = t & 1, nxt = cur ^ 1;
        if (t < 15) { stA(nxt, t + 1); stB(nxt, t + 1); }   // issue-early
        const short* Ab = Abuf(cur);
        const short* Bb = Bbuf(cur);
        #pragma unroll
        for (int ks = 0; ks < 2; ++ks) {
            short8 af[4], bf4[4];
            #pragma unroll
            for (int mt = 0; mt < 4; ++mt)
                af[mt] = *(const short8*)
                    &Ab[(wm * 64 + mt * 16 + l15) * 64 + (((ks * 4 + quad) ^ rx) * 8)];
            #pragma unroll
            for (int nt = 0; nt < 4; ++nt)
                bf4[nt] = *(const short8*)
                    &Bb[(wn * 64 + nt * 16 + l15) * 64 + (((ks * 4 + quad) ^ rx) * 8)];
            __builtin_amdgcn_s_setprio(1);
            #pragma unroll
            for (int mt = 0; mt < 4; ++mt)
                #pragma unroll
                for (int nt = 0; nt < 4; ++nt)
                    acc[mt][nt] = __builtin_amdgcn_mfma_f32_16x16x32_bf16(
                        af[mt], bf4[nt], acc[mt][nt], 0, 0, 0);
            __builtin_amdgcn_s_setprio(0);
        }
        VM0;           // tile t+1's 8 loads: issued a full tile ago -> ~0 wait
        BARRIER;       // buf[nxt] visible to all; all waves done with buf[cur]
    }

    // C layout per fragment: col = l15 (N), row = quad*4+reg (M).
    if (z != 2) {
        short* Yb = (z == 0) ? Qb : Kb;
        #pragma unroll
        for (int mt = 0; mt < 4; ++mt)
            #pragma unroll
            for (int nt = 0; nt < 4; ++nt)
                #pragma unroll
                for (int reg = 0; reg < 4; ++reg) {
                    int rg = m0 + wm * 64 + mt * 16 + quad * 4 + reg;
                    int cg = n0 + wn * 64 + nt * 16 + l15;
                    int b = rg >> 11, s = rg & 2047;
                    int h = cg >> 7,  d = cg & 127;
                    Yb[((size_t)(b * NH + h) * S_ + s) * DK + d] =
                        f2bf(acc[mt][nt][reg] * scale);
                }
        return;
    }
    // ---- z==2: V tile (1 head x 128 s-rows) -> LDS, fused db4 DWT ----
    short* Cs = SM;                      // 128 x 130 shorts = 33.3KB (in 64KB)
    #pragma unroll
    for (int mt = 0; mt < 4; ++mt)
        #pragma unroll
        for (int nt = 0; nt < 4; ++nt)
            #pragma unroll
            for (int reg = 0; reg < 4; ++reg) {
                int r = wm * 64 + mt * 16 + quad * 4 + reg;
                int c = wn * 64 + nt * 16 + l15;
                Cs[r * 130 + c] = f2bf(acc[mt][nt][reg]);
            }
    __syncthreads();
    const int rl    = tid & 127;                 // local V row (s)
    const int chunk = tid >> 7;                  // t-half 0/1
    const int rg = m0 + rl;
    const int b = rg >> 11, s = rg & 2047;
    const int bh = b * NH + (by & 7);            // h == by&7
    const short* vr = Cs + rl * 130;
    auto getv = [&](int i) -> float {
        int k = (i < 6) ? (5 - i) : (i < 134) ? (i - 6) : (261 - i);
        return bf2f(vr[k]);
    };
    const int t0 = chunk * 34;
    const int t1 = (chunk == 0) ? 34 : WA;
    float win[8];
    #pragma unroll
    for (int j = 0; j < 8; ++j) win[j] = getv(2 * t0 + j);
    float* oA = outA + ((size_t)bh * S_ + s) * WA;
    for (int t = t0; t < t1; ++t) {
        float lo = 0.f, hi = 0.f;
        #pragma unroll
        for (int j = 0; j < 8; ++j) { lo += win[j] * FLO[j]; hi += win[j] * FHI[j]; }
        oA[t] = lo;                                          // contiguous per thread
        cdt[((size_t)bh * WPAD + t) * S_ + s] = f2bf(hi);    // lane-coalesced over s
        #pragma unroll
        for (int j = 0; j < 6; ++j) win[j] = win[j + 2];
        if (t + 1 < t1) { win[6] = getv(2 * t + 8); win[7] = getv(2 * t + 9); }
    }
    if (chunk == 1) {
        #pragma unroll
        for (int w = WA; w < WPAD; ++w)
            cdt[((size_t)bh * WPAD + w) * S_ + s] =
                (w == 67) ? (short)0x3F80 : (short)0;   // ones row 67 (l), else 0
    }
}

// ---------------- flash attention: out1 = softmax(QK^T) @ cD ----------------
// 128 q-rows/block (32/wave), grid 16x32=512. SESSION-INVARIANT at ~75us:
// dbuf (r4), key-split (r9), and cross-kt pipelining (r10) all measured
// neutral vs this original single-buffer form -- keeping the simplest.
// S^T trick (A=K, B=Q) packs P as b64 into wave-private XOR-swizzled LDS.
// Unnormalized softmax (|s| < ~15, exp2 domain); the l-sum comes FREE from
// the PV MFMA via the ones-row at w=67 (col 67 of j=4 tile).
__global__ __launch_bounds__(256, 2) void attn_kernel(
    const short* __restrict__ Qb, const short* __restrict__ Kb,
    const short* __restrict__ cdt, float* __restrict__ out1)
{
    __shared__ __align__(16) short Ks[64 * 128];      // 16KB, 16 chunks/row
    __shared__ __align__(16) short Ds[WPAD * 64];     // 10KB, 8 chunks/row
    __shared__ __align__(16) short Pt[8 * 1024];      // 16KB, wave-private P
    const int tid  = threadIdx.x;
    const int wv   = tid >> 6;
    const int lane = tid & 63;
    const int l15  = lane & 15;
    const int quad = lane >> 4;
    const int qt = blockIdx.x;           // 0..15 (128 q-rows each)
    const int bh = blockIdx.y;           // 0..31
    const int b = bh >> 3, h = bh & 7;
    const int rxor = l15 & 7;

    // Q fragments from global, once. Lane layout = row l15, k = quad*8+j
    // (identical for A- and B-operands, so they serve as B in S^T = K Q^T).
    short8 aq[2][4];
    #pragma unroll
    for (int n = 0; n < 2; ++n) {
        const short* qrow =
            Qb + ((size_t)bh * S_ + qt * 128 + wv * 32 + n * 16 + l15) * DK;
        #pragma unroll
        for (int s4 = 0; s4 < 4; ++s4)
            aq[n][s4] = *(const short8*)(qrow + s4 * 32 + quad * 8);
    }

    floatx4 O[2][5] = {};                // j=4 tile col 67 accumulates l

    const short* kbase = Kb + (size_t)bh * S_ * DK;
    const int krow = lane >> 4;                    // K staging: 4 rows/issue
    const int kch  = (lane & 15);
    const int drow = lane >> 3;                    // D staging: 8 rows/issue
    const int dch  = (lane & 7) ^ (drow & 7);
    short* ptw = Pt + wv * 2048;                   // this wave's P (2 tiles)

    for (int kt = 0; kt < 32; ++kt) {
        __syncthreads();                 // prior iter done reading Ks/Ds
        #pragma unroll
        for (int i = 0; i < 4; ++i) {    // K tile: 64 rows x 256B, 16 issues
            int ti = wv * 4 + i;
            int r  = ti * 4 + krow;
            int ch = kch ^ (r & 7);
            glds16(Ks + ti * 512, kbase + ((size_t)kt * 64 + r) * DK + ch * 8);
        }
        #pragma unroll
        for (int i = 0; i < 3; ++i) {    // D tile: 80 rows x 128B, 10 issues
            int t = wv + i * 4;
            if (t < 10) {
                int r = t * 8 + drow;
                glds16(Ds + t * 512,
                       cdt + ((size_t)bh * WPAD + r) * S_ + kt * 64 + dch * 8);
            }
        }
        __syncthreads();                 // vmcnt drained -> tiles ready

        // S^T = K Q^T : C col=l15=q-row, row=quad*4+reg=key
        floatx4 sc[2][4] = {};
        #pragma unroll
        for (int s4 = 0; s4 < 4; ++s4) {
            short8 kf[4];
            #pragma unroll
            for (int mt = 0; mt < 4; ++mt) {
                int ch = (s4 * 4 + quad) ^ rxor;
                kf[mt] = *(const short8*)&Ks[(mt * 16 + l15) * 128 + ch * 8];
            }
            #pragma unroll
            for (int n = 0; n < 2; ++n)
                #pragma unroll
                for (int mt = 0; mt < 4; ++mt)
                    sc[n][mt] = __builtin_amdgcn_mfma_f32_16x16x32_bf16(
                        kf[mt], aq[n][s4], sc[n][mt], 0, 0, 0);
        }
        // p = 2^s; 4 regs = 4 consecutive keys of q-row n*16+l15 -> b64 pack
        #pragma unroll
        for (int n = 0; n < 2; ++n) {
            #pragma unroll
            for (int mt = 0; mt < 4; ++mt) {
                short4v pk;
                #pragma unroll
                for (int reg = 0; reg < 4; ++reg)
                    pk[reg] = f2bf_trunc(hexp2(sc[n][mt][reg]));
                int ch = (mt * 2 + (quad >> 1)) ^ rxor;
                *(short4v*)&ptw[n * 1024 + l15 * 64 + ch * 8 + (quad & 1) * 4] = pk;
            }
        }
        // O += P @ cD   (col 67 of j=4 accumulates l via the ones row)
        short8 ap[2][2];
        #pragma unroll
        for (int mt = 0; mt < 2; ++mt)
            #pragma unroll
            for (int ks = 0; ks < 2; ++ks) {
                int ch = (ks * 4 + quad) ^ rxor;
                ap[mt][ks] = *(const short8*)&ptw[mt * 1024 + l15 * 64 + ch * 8];
            }
        #pragma unroll
        for (int j = 0; j < 5; ++j) {
            #pragma unroll
            for (int ks = 0; ks < 2; ++ks) {
                int ch = (ks * 4 + quad) ^ rxor;
                short8 bd = *(const short8*)&Ds[(j * 16 + l15) * 64 + ch * 8];
                #pragma unroll
                for (int mt = 0; mt < 2; ++mt)
                    O[mt][j] = __builtin_amdgcn_mfma_f32_16x16x32_bf16(
                        ap[mt][ks], bd, O[mt][j], 0, 0, 0);
            }
        }
    }
    // l(r) sits at element (row r, col 67) = lane (r>>2)*16+3, reg r&3 of j=4.
    float rl[2][4];
    #pragma unroll
    for (int mt = 0; mt < 2; ++mt)
        #pragma unroll
        for (int reg = 0; reg < 4; ++reg)
            rl[mt][reg] = 1.0f / __shfl(O[mt][4][reg], (quad << 4) | 3, 64);
    // epilogue: out1[b][q][h*67+w] = O * (1/l)   (w >= 67 dropped)
    #pragma unroll
    for (int mt = 0; mt < 2; ++mt)
        #pragma unroll
        for (int j = 0; j < 5; ++j) {
            int w = j * 16 + l15;
            if (w < WA) {
                #pragma unroll
                for (int reg = 0; reg < 4; ++reg) {
                    int qrow_g = qt * 128 + wv * 32 + mt * 16 + quad * 4 + reg;
                    out1[((size_t)(b * S_ + qrow_g)) * (NH * WA) + h * WA + w] =
                        O[mt][j][reg] * rl[mt][reg];
                }
            }
        }
}

extern "C" void kernel_launch(void* const* d_in, const int* in_sizes, int n_in,
                              void* d_out, int out_size, void* d_ws, size_t ws_size,
                              hipStream_t stream)
{
    const float* x  = (const float*)d_in[0];
    const float* Wq = (const float*)d_in[1];
    const float* Wk = (const float*)d_in[2];
    const float* Wv = (const float*)d_in[3];
    float* out = (float*)d_out;

    const size_t x_elems   = (size_t)B_ * S_ * HD;           // 8,388,608
    const size_t w_elems   = (size_t)HD * HD;                // 1,048,576
    const size_t qkv_elems = (size_t)B_ * NH * S_ * DK;      // 8,388,608
    short* xb  = (short*)d_ws;
    short* Wb  = xb + x_elems;                               // 3 concatenated
    short* Qb  = Wb + 3 * w_elems;
    short* Kb  = Qb + qkv_elems;
    short* cdt = Kb + qkv_elems;                             // (b,h,w=80,s) bf16
    float* out1 = out;                                       // (B,S,536)
    float* out2 = out + (size_t)B_ * S_ * NH * WA;           // (B,H,S,67)

    cvt_all<<<dim3(5632), 256, 0, stream>>>(x, Wq, Wk, Wv, xb, Wb);
    qkv_gemm<<<dim3(64, 24), 256, 0, stream>>>(xb, Wb, Qb, Kb, out2, cdt);
    attn_kernel<<<dim3(16, 32), 256, 0, stream>>>(Qb, Kb, cdt, out1);
}